// Round 1
// baseline (1170.229 us; speedup 1.0000x reference)
//
#include <hip/hip_runtime.h>
#include <math.h>

// ---------------- wave helpers (wave = 64 on gfx950) ----------------
__device__ __forceinline__ float wmaxf(float v){
#pragma unroll
  for (int off = 1; off < 64; off <<= 1) v = fmaxf(v, __shfl_xor(v, off, 64));
  return v;
}
__device__ __forceinline__ float wsumf(float v){
#pragma unroll
  for (int off = 1; off < 64; off <<= 1) v += __shfl_xor(v, off, 64);
  return v;
}

// ---------------- CSR build ----------------
__global__ void k_zero2(int* __restrict__ a, int* __restrict__ b, int n){
  int i = blockIdx.x * blockDim.x + threadIdx.x;
  if (i < n){ a[i] = 0; b[i] = 0; }
}

__global__ void k_hist(const int* __restrict__ dst, int* __restrict__ cnt, int E){
  int i = blockIdx.x * blockDim.x + threadIdx.x;
  if (i < E) atomicAdd(&cnt[dst[i]], 1);
}

__global__ void k_scan1(const int* __restrict__ cnt, int* __restrict__ ptre,
                        int* __restrict__ sums, int n){
  __shared__ int sh[256];
  int t = threadIdx.x; int i = blockIdx.x * 256 + t;
  int v = (i < n) ? cnt[i] : 0;
  sh[t] = v; __syncthreads();
  for (int off = 1; off < 256; off <<= 1){
    int u = (t >= off) ? sh[t - off] : 0;
    __syncthreads();
    sh[t] += u;
    __syncthreads();
  }
  if (i < n) ptre[i] = sh[t] - v;           // chunk-local exclusive
  if (t == 255) sums[blockIdx.x] = sh[255]; // chunk total
}

__global__ void k_scan2(const int* __restrict__ sums, int* __restrict__ chof, int nch){
  __shared__ int sh[256];
  int t = threadIdx.x;
  int v = (t < nch) ? sums[t] : 0;
  sh[t] = v; __syncthreads();
  for (int off = 1; off < 256; off <<= 1){
    int u = (t >= off) ? sh[t - off] : 0;
    __syncthreads();
    sh[t] += u;
    __syncthreads();
  }
  if (t < nch) chof[t] = sh[t] - v;         // exclusive chunk offset
}

__global__ void k_scan3(int* __restrict__ ptre, const int* __restrict__ chof, int n, int E){
  int i = blockIdx.x * 256 + threadIdx.x;
  if (i < n) ptre[i] += chof[blockIdx.x];
  if (blockIdx.x == 0 && threadIdx.x == 0) ptre[n] = E;
}

__global__ void k_fill(const int* __restrict__ src, const int* __restrict__ dst,
                       const int* __restrict__ ptre, int* __restrict__ fpos,
                       int* __restrict__ srcs, int E){
  int i = blockIdx.x * blockDim.x + threadIdx.x;
  if (i < E){
    int d = dst[i];
    int pos = ptre[d] + atomicAdd(&fpos[d], 1);
    srcs[pos] = src[i];
  }
}

// ---------------- dense GEMM: Y[n,MDIM] = X[n,K] @ W[K,MDIM] ----------------
template<int MDIM>
__global__ __launch_bounds__(256) void k_gemm(
    const float* __restrict__ X, const float* __restrict__ W,
    float* __restrict__ Y, int n, int K)
{
  constexpr int CJ = MDIM / 32;
  __shared__ float xs[32][33];
  __shared__ float wsh[32][MDIM];
  int tid = threadIdx.x;
  int tx = tid & 31, ty = tid >> 5;
  int n0 = blockIdx.x * 32;
  float acc[4][CJ];
#pragma unroll
  for (int i = 0; i < 4; i++)
#pragma unroll
    for (int j = 0; j < CJ; j++) acc[i][j] = 0.f;
  int lr = tid >> 3;          // 0..31 row of X tile
  int lc = (tid & 7) << 2;    // k offset within tile (float4)
  for (int k0 = 0; k0 < K; k0 += 32){
    float4 xv = make_float4(0.f, 0.f, 0.f, 0.f);
    int gr = n0 + lr;
    if (gr < n) xv = *reinterpret_cast<const float4*>(X + (size_t)gr * K + k0 + lc);
    xs[lr][lc + 0] = xv.x; xs[lr][lc + 1] = xv.y;
    xs[lr][lc + 2] = xv.z; xs[lr][lc + 3] = xv.w;
    for (int idx = tid; idx < 32 * MDIM / 4; idx += 256){
      int e4 = idx * 4; int kk = e4 / MDIM; int mm = e4 - kk * MDIM;
      *reinterpret_cast<float4*>(&wsh[kk][mm]) =
          *reinterpret_cast<const float4*>(W + (size_t)(k0 + kk) * MDIM + mm);
    }
    __syncthreads();
#pragma unroll
    for (int kk = 0; kk < 32; kk++){
      float a[4];
#pragma unroll
      for (int i = 0; i < 4; i++) a[i] = xs[ty + 8 * i][kk];
#pragma unroll
      for (int j = 0; j < CJ; j++){
        float b = wsh[kk][tx + 32 * j];
#pragma unroll
        for (int i = 0; i < 4; i++) acc[i][j] += a[i] * b;
      }
    }
    __syncthreads();
  }
#pragma unroll
  for (int i = 0; i < 4; i++){
    int gr = n0 + ty + 8 * i;
    if (gr < n){
#pragma unroll
      for (int j = 0; j < CJ; j++) Y[(size_t)gr * MDIM + tx + 32 * j] = acc[i][j];
    }
  }
}

// ---------------- el/er: attention projections ----------------
template<int HNUM, int HIDD>
__global__ void k_elr(const float* __restrict__ h, const float* __restrict__ al,
                      const float* __restrict__ ar, float* __restrict__ el,
                      float* __restrict__ er, int n)
{
  int idx = blockIdx.x * blockDim.x + threadIdx.x;
  if (idx >= n * HNUM) return;
  int node = idx / HNUM;
  int hh = idx - node * HNUM;
  const float* row = h + (size_t)node * (HNUM * HIDD) + hh * HIDD;
  float se = 0.f, sr = 0.f;
#pragma unroll
  for (int d = 0; d < HIDD; d++){
    float v = row[d];
    se += v * al[hh * HIDD + d];
    sr += v * ar[hh * HIDD + d];
  }
  el[idx] = se; er[idx] = sr;
}

// ---------------- edge softmax + aggregation (one wave per dst node) --------
// EPI: 0 = ELU -> next-layer input ; 1 = softmax -> initial pseudo labels
template<int HNUM, int MDIM, int EPI>
__global__ __launch_bounds__(64) void k_edge(
    const int* __restrict__ ptre, const int* __restrict__ srcs,
    const float* __restrict__ hsrc, const float* __restrict__ el,
    const float* __restrict__ er, float* __restrict__ outp,
    float* __restrict__ wE, int init_w, int n)
{
  constexpr int HID_ = MDIM / HNUM;
  constexpr int DPL = MDIM / 64;     // dims per lane
  __shared__ float alds[128 * HNUM];
  int node = blockIdx.x;
  if (node >= n) return;
  int lane = threadIdx.x;
  int base = ptre[node];
  int deg = ptre[node + 1] - base;
  float erv[HNUM];
#pragma unroll
  for (int hh = 0; hh < HNUM; hh++) erv[hh] = er[node * HNUM + hh];

  // phase 1: per-head max of leaky(el[src]+er[dst])
  float mx[HNUM];
#pragma unroll
  for (int hh = 0; hh < HNUM; hh++) mx[hh] = -INFINITY;
  for (int i = lane; i < deg; i += 64){
    int s = srcs[base + i];
#pragma unroll
    for (int hh = 0; hh < HNUM; hh++){
      float e = el[s * HNUM + hh] + erv[hh];
      e = e > 0.f ? e : 0.2f * e;
      mx[hh] = fmaxf(mx[hh], e);
    }
  }
#pragma unroll
  for (int hh = 0; hh < HNUM; hh++) mx[hh] = wmaxf(mx[hh]);

  // phase 2: per-head sum of exp
  float sm[HNUM];
#pragma unroll
  for (int hh = 0; hh < HNUM; hh++) sm[hh] = 0.f;
  for (int i = lane; i < deg; i += 64){
    int s = srcs[base + i];
#pragma unroll
    for (int hh = 0; hh < HNUM; hh++){
      float e = el[s * HNUM + hh] + erv[hh];
      e = e > 0.f ? e : 0.2f * e;
      sm[hh] += __expf(e - mx[hh]);
    }
  }
  float inv[HNUM];
#pragma unroll
  for (int hh = 0; hh < HNUM; hh++) inv[hh] = 1.f / (wsumf(sm[hh]) + 1e-9f);

  // phase 3: alpha per edge (chunked in LDS) + weighted aggregation
  float acc[DPL];
#pragma unroll
  for (int dd = 0; dd < DPL; dd++) acc[dd] = 0.f;

  for (int c0 = 0; c0 < deg; c0 += 128){
    int cnt = min(128, deg - c0);
    for (int i = lane; i < cnt; i += 64){
      int s = srcs[base + c0 + i];
      float wsum = 0.f;
#pragma unroll
      for (int hh = 0; hh < HNUM; hh++){
        float e = el[s * HNUM + hh] + erv[hh];
        e = e > 0.f ? e : 0.2f * e;
        float a = __expf(e - mx[hh]) * inv[hh];
        alds[i * HNUM + hh] = a;
        wsum += a;
      }
      wsum *= (1.f / (3.f * HNUM));   // mean over heads, /3 over layers
      if (init_w) wE[base + c0 + i] = wsum;
      else        wE[base + c0 + i] += wsum;
    }
    __syncthreads();
    for (int j = 0; j < cnt; j++){
      int s = srcs[base + c0 + j];
#pragma unroll
      for (int dd = 0; dd < DPL; dd++){
        int dim = lane + 64 * dd;
        acc[dd] += alds[j * HNUM + dim / HID_] * hsrc[(size_t)s * MDIM + dim];
      }
    }
    __syncthreads();
  }

  if (EPI == 0){
#pragma unroll
    for (int dd = 0; dd < DPL; dd++){
      int dim = lane + 64 * dd;
      float v = acc[dd];
      v = v > 0.f ? v : expm1f(v);    // ELU
      outp[(size_t)node * MDIM + dim] = v;
    }
  } else {
    float v = acc[0];
    float m = wmaxf(v);
    float p = __expf(v - m);
    float s = wsumf(p);
    outp[(size_t)node * 64 + lane] = p / s;   // initial pseudo = softmax(logits)
  }
}

// ---------------- fused label-prop step: gather + 64x64 GEMM + softmax ------
__global__ __launch_bounds__(64) void k_lp(
    const int* __restrict__ ptre, const int* __restrict__ srcs,
    const float* __restrict__ wE, const float* __restrict__ pin,
    const float* __restrict__ Wp, const float* __restrict__ bp,
    float* __restrict__ pout, int final_step, int n)
{
  __shared__ float ash[64];
  int node = blockIdx.x;
  if (node >= n) return;
  int lane = threadIdx.x;
  int base = ptre[node];
  int deg = ptre[node + 1] - base;
  float agg = 0.f;
  for (int j = 0; j < deg; j++){
    int e = base + j;
    int s = srcs[e];
    agg += wE[e] * pin[(size_t)s * 64 + lane];
  }
  ash[lane] = agg;
  __syncthreads();
  float lg = bp[lane];
#pragma unroll 16
  for (int k = 0; k < 64; k++) lg += ash[k] * Wp[k * 64 + lane];
  float m = wmaxf(lg);
  float p = __expf(lg - m);
  float s = wsumf(p);
  if (final_step) pout[(size_t)node * 64 + lane] = (lg - m) - __logf(s);
  else            pout[(size_t)node * 64 + lane] = p / s;
}

// ---------------- launch ----------------
extern "C" void kernel_launch(void* const* d_in, const int* in_sizes, int n_in,
                              void* d_out, int out_size, void* d_ws, size_t ws_size,
                              hipStream_t stream) {
  const float* feat = (const float*)d_in[0];
  const int*   src  = (const int*)d_in[1];
  const int*   dst  = (const int*)d_in[2];
  const float* W0   = (const float*)d_in[3];
  const float* al0  = (const float*)d_in[4];
  const float* ar0  = (const float*)d_in[5];
  const float* W1   = (const float*)d_in[6];
  const float* al1  = (const float*)d_in[7];
  const float* ar1  = (const float*)d_in[8];
  const float* W2   = (const float*)d_in[9];
  const float* al2  = (const float*)d_in[10];
  const float* ar2  = (const float*)d_in[11];
  const float* Wp   = (const float*)d_in[12];
  const float* bp   = (const float*)d_in[13];
  float* out = (float*)d_out;

  const int N = in_sizes[0] / 256;   // 50000
  const int E = in_sizes[1];         // 850000
  const int NCH = (N + 255) / 256;   // scan chunks (<=256 required)

  // carve workspace (256B aligned)
  char* p = (char*)d_ws;
  auto carve = [&](size_t bytes) -> void* {
    void* r = (void*)p;
    p += (bytes + 255) & ~(size_t)255;
    return r;
  };
  int*   ptr_i = (int*)carve((size_t)(N + 1) * 4);
  int*   cntA  = (int*)carve((size_t)N * 4);
  int*   cntB  = (int*)carve((size_t)N * 4);
  int*   sums  = (int*)carve(1024);
  int*   chof  = (int*)carve(1024);
  int*   srcs  = (int*)carve((size_t)E * 4);
  float* wE    = (float*)carve((size_t)E * 4);
  float* hbuf  = (float*)carve((size_t)N * 128 * 4);
  float* xbuf  = (float*)carve((size_t)N * 128 * 4);
  float* el    = (float*)carve((size_t)N * 4 * 4);
  float* er    = (float*)carve((size_t)N * 4 * 4);
  float* pA    = (float*)carve((size_t)N * 64 * 4);
  float* pB    = (float*)carve((size_t)N * 64 * 4);
  (void)ws_size; (void)n_in; (void)out_size;

  // ---- CSR by dst ----
  k_zero2<<<(N + 255) / 256, 256, 0, stream>>>(cntA, cntB, N);
  k_hist<<<(E + 255) / 256, 256, 0, stream>>>(dst, cntA, E);
  k_scan1<<<NCH, 256, 0, stream>>>(cntA, ptr_i, sums, N);
  k_scan2<<<1, 256, 0, stream>>>(sums, chof, NCH);
  k_scan3<<<NCH, 256, 0, stream>>>(ptr_i, chof, N, E);
  k_fill<<<(E + 255) / 256, 256, 0, stream>>>(src, dst, ptr_i, cntB, srcs, E);

  const int GGRID = (N + 31) / 32;
  // ---- layer 0: 256 -> [4,32] ----
  k_gemm<128><<<GGRID, 256, 0, stream>>>(feat, W0, hbuf, N, 256);
  k_elr<4, 32><<<(N * 4 + 255) / 256, 256, 0, stream>>>(hbuf, al0, ar0, el, er, N);
  k_edge<4, 128, 0><<<N, 64, 0, stream>>>(ptr_i, srcs, hbuf, el, er, xbuf, wE, 1, N);
  // ---- layer 1: 128 -> [4,32] ----
  k_gemm<128><<<GGRID, 256, 0, stream>>>(xbuf, W1, hbuf, N, 128);
  k_elr<4, 32><<<(N * 4 + 255) / 256, 256, 0, stream>>>(hbuf, al1, ar1, el, er, N);
  k_edge<4, 128, 0><<<N, 64, 0, stream>>>(ptr_i, srcs, hbuf, el, er, xbuf, wE, 0, N);
  // ---- layer 2: 128 -> [1,64] ----
  k_gemm<64><<<GGRID, 256, 0, stream>>>(xbuf, W2, hbuf, N, 128);
  k_elr<1, 64><<<(N + 255) / 256, 256, 0, stream>>>(hbuf, al2, ar2, el, er, N);
  k_edge<1, 64, 1><<<N, 64, 0, stream>>>(ptr_i, srcs, hbuf, el, er, pA, wE, 0, N);

  // ---- 10 label-prop steps (ping-pong; final writes log-softmax to d_out) --
  float* cur = pA; float* nxt = pB;
  for (int st = 0; st < 10; st++){
    int fin = (st == 9);
    float* o = fin ? out : nxt;
    k_lp<<<N, 64, 0, stream>>>(ptr_i, srcs, wE, cur, Wp, bp, o, fin, N);
    float* t = cur; cur = nxt; nxt = t;
  }
}

// Round 2
// 965.848 us; speedup vs baseline: 1.2116x; 1.2116x over previous
//
#include <hip/hip_runtime.h>
#include <math.h>

// ---------------- wave helpers (wave = 64 on gfx950) ----------------
__device__ __forceinline__ float wmaxf(float v){
#pragma unroll
  for (int off = 1; off < 64; off <<= 1) v = fmaxf(v, __shfl_xor(v, off, 64));
  return v;
}
__device__ __forceinline__ float wsumf(float v){
#pragma unroll
  for (int off = 1; off < 64; off <<= 1) v += __shfl_xor(v, off, 64);
  return v;
}

// ---------------- CSR build ----------------
__global__ void k_zero2(int* __restrict__ a, int* __restrict__ b, int n){
  int i = blockIdx.x * blockDim.x + threadIdx.x;
  if (i < n){ a[i] = 0; b[i] = 0; }
}

__global__ void k_hist(const int* __restrict__ dst, int* __restrict__ cnt, int E){
  int i = blockIdx.x * blockDim.x + threadIdx.x;
  if (i < E) atomicAdd(&cnt[dst[i]], 1);
}

__global__ void k_scan1(const int* __restrict__ cnt, int* __restrict__ ptre,
                        int* __restrict__ sums, int n){
  __shared__ int sh[256];
  int t = threadIdx.x; int i = blockIdx.x * 256 + t;
  int v = (i < n) ? cnt[i] : 0;
  sh[t] = v; __syncthreads();
  for (int off = 1; off < 256; off <<= 1){
    int u = (t >= off) ? sh[t - off] : 0;
    __syncthreads();
    sh[t] += u;
    __syncthreads();
  }
  if (i < n) ptre[i] = sh[t] - v;
  if (t == 255) sums[blockIdx.x] = sh[255];
}

__global__ void k_scan2(const int* __restrict__ sums, int* __restrict__ chof, int nch){
  __shared__ int sh[256];
  int t = threadIdx.x;
  int v = (t < nch) ? sums[t] : 0;
  sh[t] = v; __syncthreads();
  for (int off = 1; off < 256; off <<= 1){
    int u = (t >= off) ? sh[t - off] : 0;
    __syncthreads();
    sh[t] += u;
    __syncthreads();
  }
  if (t < nch) chof[t] = sh[t] - v;
}

__global__ void k_scan3(int* __restrict__ ptre, const int* __restrict__ chof, int n, int E){
  int i = blockIdx.x * 256 + threadIdx.x;
  if (i < n) ptre[i] += chof[blockIdx.x];
  if (blockIdx.x == 0 && threadIdx.x == 0) ptre[n] = E;
}

__global__ void k_fill(const int* __restrict__ src, const int* __restrict__ dst,
                       const int* __restrict__ ptre, int* __restrict__ fpos,
                       int* __restrict__ srcs, int E){
  int i = blockIdx.x * blockDim.x + threadIdx.x;
  if (i < E){
    int d = dst[i];
    int pos = ptre[d] + atomicAdd(&fpos[d], 1);
    srcs[pos] = src[i];
  }
}

__global__ void k_pack(const int* __restrict__ srcs, const float* __restrict__ wE,
                       int2* __restrict__ epk, int E){
  int i = blockIdx.x * blockDim.x + threadIdx.x;
  if (i < E) epk[i] = make_int2(srcs[i], __float_as_int(wE[i]));
}

// ---------------- dense GEMM: Y[n,MDIM] = X[n,K] @ W[K,MDIM] ----------------
// 64-row tile, k-major LDS X (ds_read_b128 A-fragments), register tile RTx4.
// EPI: 0 = plain store; 1 = +bias, row softmax (MDIM=64 only);
//      2 = +bias, row log-softmax (MDIM=64 only).
template<int MDIM, int EPI>
__global__ __launch_bounds__(256) void k_gemm(
    const float* __restrict__ X, const float* __restrict__ W,
    const float* __restrict__ bias, float* __restrict__ Y, int n, int K)
{
  constexpr int CO = MDIM / 4;     // col-groups (32 or 16)
  constexpr int RO = 256 / CO;     // row-thread groups
  constexpr int RT = 64 / RO;      // rows per thread (8 or 4)
  __shared__ float xs[32][68];     // k-major X tile (pad keeps 16B align, no conflicts)
  __shared__ float wsh[32][MDIM];
  int tid = threadIdx.x;
  int c = tid % CO, r = tid / CO;
  int n0 = blockIdx.x * 64;
  float acc[RT][4];
#pragma unroll
  for (int i = 0; i < RT; i++)
#pragma unroll
    for (int j = 0; j < 4; j++) acc[i][j] = 0.f;
  int lrow = tid & 63;
  int kq4 = (tid >> 6) << 2;       // 0,4,8,12
  for (int k0 = 0; k0 < K; k0 += 32){
    const float* Xr = X + (size_t)min(n0 + lrow, n - 1) * K + k0 + kq4;
#pragma unroll
    for (int kb = 0; kb < 32; kb += 16){
      float4 xv = *reinterpret_cast<const float4*>(Xr + kb);
      xs[kb + kq4 + 0][lrow] = xv.x;
      xs[kb + kq4 + 1][lrow] = xv.y;
      xs[kb + kq4 + 2][lrow] = xv.z;
      xs[kb + kq4 + 3][lrow] = xv.w;
    }
#pragma unroll
    for (int t = 0; t < MDIM / 32; t++){
      int idx = (tid + t * 256) * 4;
      int kk = idx / MDIM, mm = idx % MDIM;
      *reinterpret_cast<float4*>(&wsh[kk][mm]) =
          *reinterpret_cast<const float4*>(W + (size_t)(k0 + kk) * MDIM + mm);
    }
    __syncthreads();
#pragma unroll
    for (int kk = 0; kk < 32; kk++){
      float4 b = *reinterpret_cast<float4*>(&wsh[kk][4 * c]);
      float a[RT];
#pragma unroll
      for (int i = 0; i < RT; i += 4){
        float4 av = *reinterpret_cast<float4*>(&xs[kk][RT * r + i]);
        a[i] = av.x; a[i + 1] = av.y; a[i + 2] = av.z; a[i + 3] = av.w;
      }
#pragma unroll
      for (int i = 0; i < RT; i++){
        acc[i][0] += a[i] * b.x;
        acc[i][1] += a[i] * b.y;
        acc[i][2] += a[i] * b.z;
        acc[i][3] += a[i] * b.w;
      }
    }
    __syncthreads();
  }
  if (EPI == 0){
#pragma unroll
    for (int i = 0; i < RT; i++){
      int gr = n0 + RT * r + i;
      if (gr < n)
        *reinterpret_cast<float4*>(Y + (size_t)gr * MDIM + 4 * c) =
            make_float4(acc[i][0], acc[i][1], acc[i][2], acc[i][3]);
    }
  } else {
    // MDIM=64: 16 col-lanes per row share a quarter-wave -> shfl_xor 1,2,4,8
    float4 bb = *reinterpret_cast<const float4*>(bias + 4 * c);
#pragma unroll
    for (int i = 0; i < RT; i++){
      float v0 = acc[i][0] + bb.x, v1 = acc[i][1] + bb.y,
            v2 = acc[i][2] + bb.z, v3 = acc[i][3] + bb.w;
      float m = fmaxf(fmaxf(v0, v1), fmaxf(v2, v3));
#pragma unroll
      for (int off = 1; off < 16; off <<= 1) m = fmaxf(m, __shfl_xor(m, off, 64));
      float p0 = __expf(v0 - m), p1 = __expf(v1 - m),
            p2 = __expf(v2 - m), p3 = __expf(v3 - m);
      float s = p0 + p1 + p2 + p3;
#pragma unroll
      for (int off = 1; off < 16; off <<= 1) s += __shfl_xor(s, off, 64);
      int gr = n0 + RT * r + i;
      if (gr < n){
        float4 o;
        if (EPI == 1){
          float is = 1.f / s;
          o = make_float4(p0 * is, p1 * is, p2 * is, p3 * is);
        } else {
          float ls = __logf(s);
          o = make_float4(v0 - m - ls, v1 - m - ls, v2 - m - ls, v3 - m - ls);
        }
        *reinterpret_cast<float4*>(Y + (size_t)gr * 64 + 4 * c) = o;
      }
    }
  }
}

// ---------------- el/er: attention projections ----------------
template<int HNUM, int HIDD>
__global__ void k_elr(const float* __restrict__ h, const float* __restrict__ al,
                      const float* __restrict__ ar, float* __restrict__ el,
                      float* __restrict__ er, int n)
{
  int idx = blockIdx.x * blockDim.x + threadIdx.x;
  if (idx >= n * HNUM) return;
  int node = idx / HNUM, hh = idx - node * HNUM;
  const float4* row = reinterpret_cast<const float4*>(h + (size_t)node * (HNUM * HIDD) + hh * HIDD);
  const float4* a4 = reinterpret_cast<const float4*>(al + hh * HIDD);
  const float4* r4 = reinterpret_cast<const float4*>(ar + hh * HIDD);
  float se = 0.f, sr = 0.f;
#pragma unroll
  for (int d = 0; d < HIDD / 4; d++){
    float4 v = row[d], x = a4[d], y = r4[d];
    se += v.x * x.x + v.y * x.y + v.z * x.z + v.w * x.w;
    sr += v.x * y.x + v.y * y.y + v.z * y.z + v.w * y.w;
  }
  el[idx] = se; er[idx] = sr;
}

// ---------------- edge softmax + aggregation (one wave per dst node) --------
// Online softmax (single el pass), float4 el loads, edge-parallel float4
// h gathers (EP edges across lane groups), shuffle cross-group reduce.
// EPI: 0 = ELU store [N,MDIM]; 1 = softmax -> initial pseudo [N,64].
template<int HNUM, int MDIM, int EPI>
__global__ __launch_bounds__(64) void k_edge(
    const int* __restrict__ ptre, const int* __restrict__ srcs,
    const float* __restrict__ hsrc, const float* __restrict__ el,
    const float* __restrict__ er, float* __restrict__ outp,
    float* __restrict__ wE, int init_w, int n)
{
  constexpr int EP = (MDIM == 128) ? 2 : 4;  // edges in parallel
  constexpr int LL = 64 / EP;                // lanes per edge
  __shared__ float alds[128 * HNUM];
  __shared__ int   sids[128];
  int node = blockIdx.x;
  if (node >= n) return;
  int lane = threadIdx.x;
  int base = ptre[node];
  int deg  = ptre[node + 1] - base;

  float erv[HNUM];
  if (HNUM == 4){
    float4 t = *reinterpret_cast<const float4*>(er + node * 4);
    erv[0] = t.x; erv[1] = t.y; erv[2] = t.z; erv[3] = t.w;
  } else erv[0] = er[node];

  // online max+sum over incoming edges (lane-strided)
  float mx[HNUM], sm[HNUM];
#pragma unroll
  for (int h = 0; h < HNUM; h++){ mx[h] = -INFINITY; sm[h] = 0.f; }
  for (int i = lane; i < deg; i += 64){
    int s = srcs[base + i];
    float e[HNUM];
    if (HNUM == 4){
      float4 t = *reinterpret_cast<const float4*>(el + s * 4);
      e[0] = t.x; e[1] = t.y; e[2] = t.z; e[3] = t.w;
    } else e[0] = el[s];
#pragma unroll
    for (int h = 0; h < HNUM; h++){
      float v = e[h] + erv[h];
      v = v > 0.f ? v : 0.2f * v;
      float mn = fmaxf(mx[h], v);
      sm[h] = sm[h] * __expf(mx[h] - mn) + __expf(v - mn);
      mx[h] = mn;
    }
  }
  float M[HNUM], inv[HNUM];
#pragma unroll
  for (int h = 0; h < HNUM; h++){
    M[h] = wmaxf(mx[h]);
    float sc = sm[h] * __expf(mx[h] - M[h]);
    inv[h] = 1.f / (wsumf(sc) + 1e-9f);
  }

  int l = lane % LL, g = lane / LL;
  float ax = 0.f, ay = 0.f, az = 0.f, aw = 0.f;
  for (int c0 = 0; c0 < deg; c0 += 128){
    int cnt = min(128, deg - c0);
    for (int i = lane; i < cnt; i += 64){
      int s = srcs[base + c0 + i];
      sids[i] = s;
      float e[HNUM], a[HNUM], wsum = 0.f;
      if (HNUM == 4){
        float4 t = *reinterpret_cast<const float4*>(el + s * 4);
        e[0] = t.x; e[1] = t.y; e[2] = t.z; e[3] = t.w;
      } else e[0] = el[s];
#pragma unroll
      for (int h = 0; h < HNUM; h++){
        float v = e[h] + erv[h];
        v = v > 0.f ? v : 0.2f * v;
        a[h] = __expf(v - M[h]) * inv[h];
        wsum += a[h];
      }
      if (HNUM == 4)
        *reinterpret_cast<float4*>(&alds[i * 4]) = make_float4(a[0], a[1], a[2], a[3]);
      else
        alds[i] = a[0];
      wsum *= (1.f / (3.f * HNUM));
      int eidx = base + c0 + i;
      wE[eidx] = init_w ? wsum : (wE[eidx] + wsum);
    }
    __syncthreads();
    for (int j0 = 0; j0 < cnt; j0 += EP){
      int j = j0 + g;
      if (j < cnt){
        int s = sids[j];
        float a = (HNUM == 4) ? alds[j * 4 + (l >> 3)] : alds[j];
        float4 v = *reinterpret_cast<const float4*>(hsrc + (size_t)s * MDIM + 4 * l);
        ax += a * v.x; ay += a * v.y; az += a * v.z; aw += a * v.w;
      }
    }
    __syncthreads();
  }
#pragma unroll
  for (int off = LL; off < 64; off <<= 1){
    ax += __shfl_xor(ax, off, 64);
    ay += __shfl_xor(ay, off, 64);
    az += __shfl_xor(az, off, 64);
    aw += __shfl_xor(aw, off, 64);
  }
  if (EPI == 0){
    if (g == 0){
      float4 o;
      o.x = ax > 0.f ? ax : expm1f(ax);
      o.y = ay > 0.f ? ay : expm1f(ay);
      o.z = az > 0.f ? az : expm1f(az);
      o.w = aw > 0.f ? aw : expm1f(aw);
      *reinterpret_cast<float4*>(outp + (size_t)node * MDIM + 4 * l) = o;
    }
  } else {
    float lm = fmaxf(fmaxf(ax, ay), fmaxf(az, aw));
    float Mx = wmaxf(lm);
    float p0 = __expf(ax - Mx), p1 = __expf(ay - Mx),
          p2 = __expf(az - Mx), p3 = __expf(aw - Mx);
    float S = wsumf(p0 + p1 + p2 + p3) * (1.f / EP);
    float is = 1.f / S;
    if (g == 0)
      *reinterpret_cast<float4*>(outp + (size_t)node * 64 + 4 * l) =
          make_float4(p0 * is, p1 * is, p2 * is, p3 * is);
  }
}

// ---------------- LP aggregation: agg[dst] = sum_e w[e]*pin[src] ------------
// 4 waves/block (1 node each), 4 edges in parallel across 16-lane groups.
__global__ __launch_bounds__(256) void k_agg(
    const int* __restrict__ ptre, const int2* __restrict__ epk,
    const float* __restrict__ pin, float* __restrict__ agg, int n)
{
  int w = threadIdx.x >> 6, lane = threadIdx.x & 63;
  int node = blockIdx.x * 4 + w;
  if (node >= n) return;
  int l = lane & 15, g = lane >> 4;
  int base = ptre[node], deg = ptre[node + 1] - base;
  float ax = 0.f, ay = 0.f, az = 0.f, aw = 0.f;
  for (int j0 = 0; j0 < deg; j0 += 4){
    int j = j0 + g;
    if (j < deg){
      int2 ep = epk[base + j];
      float wv = __int_as_float(ep.y);
      float4 v = *reinterpret_cast<const float4*>(pin + (size_t)ep.x * 64 + 4 * l);
      ax += wv * v.x; ay += wv * v.y; az += wv * v.z; aw += wv * v.w;
    }
  }
#pragma unroll
  for (int off = 16; off < 64; off <<= 1){
    ax += __shfl_xor(ax, off, 64);
    ay += __shfl_xor(ay, off, 64);
    az += __shfl_xor(az, off, 64);
    aw += __shfl_xor(aw, off, 64);
  }
  if (g == 0)
    *reinterpret_cast<float4*>(agg + (size_t)node * 64 + 4 * l) =
        make_float4(ax, ay, az, aw);
}

// ---------------- launch ----------------
extern "C" void kernel_launch(void* const* d_in, const int* in_sizes, int n_in,
                              void* d_out, int out_size, void* d_ws, size_t ws_size,
                              hipStream_t stream) {
  const float* feat = (const float*)d_in[0];
  const int*   src  = (const int*)d_in[1];
  const int*   dst  = (const int*)d_in[2];
  const float* W0   = (const float*)d_in[3];
  const float* al0  = (const float*)d_in[4];
  const float* ar0  = (const float*)d_in[5];
  const float* W1   = (const float*)d_in[6];
  const float* al1  = (const float*)d_in[7];
  const float* ar1  = (const float*)d_in[8];
  const float* W2   = (const float*)d_in[9];
  const float* al2  = (const float*)d_in[10];
  const float* ar2  = (const float*)d_in[11];
  const float* Wp   = (const float*)d_in[12];
  const float* bp   = (const float*)d_in[13];
  float* out = (float*)d_out;

  const int N = in_sizes[0] / 256;   // 50000
  const int E = in_sizes[1];         // 850000
  const int NCH = (N + 255) / 256;

  char* p = (char*)d_ws;
  auto carve = [&](size_t bytes) -> void* {
    void* r = (void*)p;
    p += (bytes + 255) & ~(size_t)255;
    return r;
  };
  int*   ptr_i = (int*)carve((size_t)(N + 1) * 4);
  int*   cntA  = (int*)carve((size_t)N * 4);
  int*   cntB  = (int*)carve((size_t)N * 4);
  int*   sums  = (int*)carve(1024);
  int*   chof  = (int*)carve(1024);
  int*   srcs  = (int*)carve((size_t)E * 4);
  float* wE    = (float*)carve((size_t)E * 4);
  float* hbuf  = (float*)carve((size_t)N * 128 * 4);
  float* xbuf  = (float*)carve((size_t)N * 128 * 4);
  float* el    = (float*)carve((size_t)N * 4 * 4);
  float* er    = (float*)carve((size_t)N * 4 * 4);
  float* pA    = (float*)carve((size_t)N * 64 * 4);
  float* pB    = (float*)carve((size_t)N * 64 * 4);
  // reuse: epk overlays xbuf (free after L2 GEMM); aggbuf overlays hbuf
  int2*  epk    = (int2*)xbuf;
  float* aggbuf = hbuf;
  (void)ws_size; (void)n_in; (void)out_size;

  // ---- CSR by dst ----
  k_zero2<<<(N + 255) / 256, 256, 0, stream>>>(cntA, cntB, N);
  k_hist<<<(E + 255) / 256, 256, 0, stream>>>(dst, cntA, E);
  k_scan1<<<NCH, 256, 0, stream>>>(cntA, ptr_i, sums, N);
  k_scan2<<<1, 256, 0, stream>>>(sums, chof, NCH);
  k_scan3<<<NCH, 256, 0, stream>>>(ptr_i, chof, N, E);
  k_fill<<<(E + 255) / 256, 256, 0, stream>>>(src, dst, ptr_i, cntB, srcs, E);

  const int GG = (N + 63) / 64;
  // ---- layer 0: 256 -> [4,32] ----
  k_gemm<128, 0><<<GG, 256, 0, stream>>>(feat, W0, nullptr, hbuf, N, 256);
  k_elr<4, 32><<<(N * 4 + 255) / 256, 256, 0, stream>>>(hbuf, al0, ar0, el, er, N);
  k_edge<4, 128, 0><<<N, 64, 0, stream>>>(ptr_i, srcs, hbuf, el, er, xbuf, wE, 1, N);
  // ---- layer 1: 128 -> [4,32] ----
  k_gemm<128, 0><<<GG, 256, 0, stream>>>(xbuf, W1, nullptr, hbuf, N, 128);
  k_elr<4, 32><<<(N * 4 + 255) / 256, 256, 0, stream>>>(hbuf, al1, ar1, el, er, N);
  k_edge<4, 128, 0><<<N, 64, 0, stream>>>(ptr_i, srcs, hbuf, el, er, xbuf, wE, 0, N);
  // ---- layer 2: 128 -> [1,64] ----
  k_gemm<64, 0><<<GG, 256, 0, stream>>>(xbuf, W2, nullptr, hbuf, N, 128);
  k_elr<1, 64><<<(N + 255) / 256, 256, 0, stream>>>(hbuf, al2, ar2, el, er, N);
  k_edge<1, 64, 1><<<N, 64, 0, stream>>>(ptr_i, srcs, hbuf, el, er, pA, wE, 0, N);

  // ---- pack (src, w) for LP gathers; epk overlays xbuf (now dead) ----
  k_pack<<<(E + 255) / 256, 256, 0, stream>>>(srcs, wE, epk, E);

  // ---- 10 label-prop steps: gather-agg then 64x64 linear + softmax --------
  float* cur = pA; float* nxt = pB;
  for (int st = 0; st < 10; st++){
    k_agg<<<(N + 3) / 4, 256, 0, stream>>>(ptr_i, epk, cur, aggbuf, N);
    if (st == 9)
      k_gemm<64, 2><<<GG, 256, 0, stream>>>(aggbuf, Wp, bp, out, N, 64);
    else
      k_gemm<64, 1><<<GG, 256, 0, stream>>>(aggbuf, Wp, bp, nxt, N, 64);
    float* t = cur; cur = nxt; nxt = t;
  }
}

// Round 3
// 840.039 us; speedup vs baseline: 1.3931x; 1.1498x over previous
//
#include <hip/hip_runtime.h>
#include <math.h>

// ---------------- bf16 helpers ----------------
__device__ __forceinline__ float bflo(unsigned u){ return __int_as_float(u << 16); }
__device__ __forceinline__ float bfhi(unsigned u){ return __int_as_float(u & 0xffff0000u); }
__device__ __forceinline__ unsigned f2bf_u(float x){
  unsigned u = __float_as_uint(x);
  return (u + 0x7fffu + ((u >> 16) & 1u)) >> 16;
}
__device__ __forceinline__ unsigned packbf2(float a, float b){
  return f2bf_u(a) | (f2bf_u(b) << 16);
}

// ---------------- wave helpers (wave = 64 on gfx950) ----------------
__device__ __forceinline__ float wmaxf(float v){
#pragma unroll
  for (int off = 1; off < 64; off <<= 1) v = fmaxf(v, __shfl_xor(v, off, 64));
  return v;
}
__device__ __forceinline__ float wsumf(float v){
#pragma unroll
  for (int off = 1; off < 64; off <<= 1) v += __shfl_xor(v, off, 64);
  return v;
}

// ---------------- CSR build ----------------
__global__ void k_zero2(int* __restrict__ a, int* __restrict__ b, int n){
  int i = blockIdx.x * blockDim.x + threadIdx.x;
  if (i < n){ a[i] = 0; b[i] = 0; }
}

__global__ void k_hist(const int* __restrict__ dst, int* __restrict__ cnt, int E){
  int i = blockIdx.x * blockDim.x + threadIdx.x;
  if (i < E) atomicAdd(&cnt[dst[i]], 1);
}

__global__ void k_scan1(const int* __restrict__ cnt, int* __restrict__ ptre,
                        int* __restrict__ sums, int n){
  __shared__ int sh[256];
  int t = threadIdx.x; int i = blockIdx.x * 256 + t;
  int v = (i < n) ? cnt[i] : 0;
  sh[t] = v; __syncthreads();
  for (int off = 1; off < 256; off <<= 1){
    int u = (t >= off) ? sh[t - off] : 0;
    __syncthreads();
    sh[t] += u;
    __syncthreads();
  }
  if (i < n) ptre[i] = sh[t] - v;
  if (t == 255) sums[blockIdx.x] = sh[255];
}

__global__ void k_scan2(const int* __restrict__ sums, int* __restrict__ chof, int nch){
  __shared__ int sh[256];
  int t = threadIdx.x;
  int v = (t < nch) ? sums[t] : 0;
  sh[t] = v; __syncthreads();
  for (int off = 1; off < 256; off <<= 1){
    int u = (t >= off) ? sh[t - off] : 0;
    __syncthreads();
    sh[t] += u;
    __syncthreads();
  }
  if (t < nch) chof[t] = sh[t] - v;
}

__global__ void k_scan3(int* __restrict__ ptre, const int* __restrict__ chof, int n, int E){
  int i = blockIdx.x * 256 + threadIdx.x;
  if (i < n) ptre[i] += chof[blockIdx.x];
  if (blockIdx.x == 0 && threadIdx.x == 0) ptre[n] = E;
}

__global__ void k_fill(const int* __restrict__ src, const int* __restrict__ dst,
                       const int* __restrict__ ptre, int* __restrict__ fpos,
                       int* __restrict__ srcs, int E){
  int i = blockIdx.x * blockDim.x + threadIdx.x;
  if (i < E){
    int d = dst[i];
    int pos = ptre[d] + atomicAdd(&fpos[d], 1);
    srcs[pos] = src[i];
  }
}

__global__ void k_pack(const int* __restrict__ srcs, const float* __restrict__ wE,
                       int2* __restrict__ epk, int E){
  int i = blockIdx.x * blockDim.x + threadIdx.x;
  if (i < E) epk[i] = make_int2(srcs[i], __float_as_int(wE[i]));
}

// ---------------- dense GEMM: Y[n,MDIM] = X[n,K] @ W[K,MDIM] ----------------
// EPI 0: store fp32 Y (+ packed bf16 Yb if non-null)
// EPI 1: +bias, row softmax -> bf16 Yb only (MDIM=64)
// EPI 2: +bias, row log-softmax -> fp32 Y (MDIM=64)
template<int MDIM, int EPI>
__global__ __launch_bounds__(256) void k_gemm(
    const float* __restrict__ X, const float* __restrict__ W,
    const float* __restrict__ bias, float* __restrict__ Y,
    unsigned int* __restrict__ Yb, int n, int K)
{
  constexpr int CO = MDIM / 4;
  constexpr int RO = 256 / CO;
  constexpr int RT = 64 / RO;
  __shared__ float xs[32][68];
  __shared__ float wsh[32][MDIM];
  int tid = threadIdx.x;
  int c = tid % CO, r = tid / CO;
  int n0 = blockIdx.x * 64;
  float acc[RT][4];
#pragma unroll
  for (int i = 0; i < RT; i++)
#pragma unroll
    for (int j = 0; j < 4; j++) acc[i][j] = 0.f;
  int lrow = tid & 63;
  int kq4 = (tid >> 6) << 2;
  for (int k0 = 0; k0 < K; k0 += 32){
    const float* Xr = X + (size_t)min(n0 + lrow, n - 1) * K + k0 + kq4;
#pragma unroll
    for (int kb = 0; kb < 32; kb += 16){
      float4 xv = *reinterpret_cast<const float4*>(Xr + kb);
      xs[kb + kq4 + 0][lrow] = xv.x;
      xs[kb + kq4 + 1][lrow] = xv.y;
      xs[kb + kq4 + 2][lrow] = xv.z;
      xs[kb + kq4 + 3][lrow] = xv.w;
    }
#pragma unroll
    for (int t = 0; t < MDIM / 32; t++){
      int idx = (tid + t * 256) * 4;
      int kk = idx / MDIM, mm = idx % MDIM;
      *reinterpret_cast<float4*>(&wsh[kk][mm]) =
          *reinterpret_cast<const float4*>(W + (size_t)(k0 + kk) * MDIM + mm);
    }
    __syncthreads();
#pragma unroll
    for (int kk = 0; kk < 32; kk++){
      float4 b = *reinterpret_cast<float4*>(&wsh[kk][4 * c]);
      float a[RT];
#pragma unroll
      for (int i = 0; i < RT; i += 4){
        float4 av = *reinterpret_cast<float4*>(&xs[kk][RT * r + i]);
        a[i] = av.x; a[i + 1] = av.y; a[i + 2] = av.z; a[i + 3] = av.w;
      }
#pragma unroll
      for (int i = 0; i < RT; i++){
        acc[i][0] += a[i] * b.x;
        acc[i][1] += a[i] * b.y;
        acc[i][2] += a[i] * b.z;
        acc[i][3] += a[i] * b.w;
      }
    }
    __syncthreads();
  }
  if (EPI == 0){
#pragma unroll
    for (int i = 0; i < RT; i++){
      int gr = n0 + RT * r + i;
      if (gr < n){
        *reinterpret_cast<float4*>(Y + (size_t)gr * MDIM + 4 * c) =
            make_float4(acc[i][0], acc[i][1], acc[i][2], acc[i][3]);
        if (Yb){
          uint2 pk = make_uint2(packbf2(acc[i][0], acc[i][1]),
                                packbf2(acc[i][2], acc[i][3]));
          *reinterpret_cast<uint2*>((unsigned short*)Yb + (size_t)gr * MDIM + 4 * c) = pk;
        }
      }
    }
  } else {
    float4 bb = *reinterpret_cast<const float4*>(bias + 4 * c);
#pragma unroll
    for (int i = 0; i < RT; i++){
      float v0 = acc[i][0] + bb.x, v1 = acc[i][1] + bb.y,
            v2 = acc[i][2] + bb.z, v3 = acc[i][3] + bb.w;
      float m = fmaxf(fmaxf(v0, v1), fmaxf(v2, v3));
#pragma unroll
      for (int off = 1; off < 16; off <<= 1) m = fmaxf(m, __shfl_xor(m, off, 64));
      float p0 = __expf(v0 - m), p1 = __expf(v1 - m),
            p2 = __expf(v2 - m), p3 = __expf(v3 - m);
      float s = p0 + p1 + p2 + p3;
#pragma unroll
      for (int off = 1; off < 16; off <<= 1) s += __shfl_xor(s, off, 64);
      int gr = n0 + RT * r + i;
      if (gr < n){
        if (EPI == 1){
          float is = 1.f / s;
          uint2 pk = make_uint2(packbf2(p0 * is, p1 * is), packbf2(p2 * is, p3 * is));
          *reinterpret_cast<uint2*>((unsigned short*)Yb + (size_t)gr * 64 + 4 * c) = pk;
        } else {
          float ls = __logf(s);
          *reinterpret_cast<float4*>(Y + (size_t)gr * 64 + 4 * c) =
              make_float4(v0 - m - ls, v1 - m - ls, v2 - m - ls, v3 - m - ls);
        }
      }
    }
  }
}

// ---------------- el/er: attention projections ----------------
template<int HNUM, int HIDD>
__global__ void k_elr(const float* __restrict__ h, const float* __restrict__ al,
                      const float* __restrict__ ar, float* __restrict__ el,
                      float* __restrict__ er, int n)
{
  int idx = blockIdx.x * blockDim.x + threadIdx.x;
  if (idx >= n * HNUM) return;
  int node = idx / HNUM, hh = idx - node * HNUM;
  const float4* row = reinterpret_cast<const float4*>(h + (size_t)node * (HNUM * HIDD) + hh * HIDD);
  const float4* a4 = reinterpret_cast<const float4*>(al + hh * HIDD);
  const float4* r4 = reinterpret_cast<const float4*>(ar + hh * HIDD);
  float se = 0.f, sr = 0.f;
#pragma unroll
  for (int d = 0; d < HIDD / 4; d++){
    float4 v = row[d], x = a4[d], y = r4[d];
    se += v.x * x.x + v.y * x.y + v.z * x.z + v.w * x.w;
    sr += v.x * y.x + v.y * y.y + v.z * y.z + v.w * y.w;
  }
  el[idx] = se; er[idx] = sr;
}

// ---------------- edge softmax + aggregation (one wave per dst node) --------
// bf16 h gathers (16B uint4 per lane), fp32 accumulate.
// EPI: 0 = ELU store fp32 [N,MDIM]; 1 = softmax -> bf16 pseudo [N,64].
template<int HNUM, int MDIM, int EPI>
__global__ __launch_bounds__(64) void k_edge(
    const int* __restrict__ ptre, const int* __restrict__ srcs,
    const uint4* __restrict__ hb, const float* __restrict__ el,
    const float* __restrict__ er, float* __restrict__ outp,
    unsigned int* __restrict__ outb, float* __restrict__ wE, int init_w, int n)
{
  constexpr int LL = MDIM / 8;        // lanes per edge (16 or 8)
  constexpr int EP = 64 / LL;         // edges in parallel (4 or 8)
  constexpr int RS = MDIM / 8;        // row stride in uint4
  __shared__ float alds[128 * HNUM];
  __shared__ int   sids[128];
  int node = blockIdx.x;
  if (node >= n) return;
  int lane = threadIdx.x;
  int base = ptre[node];
  int deg  = ptre[node + 1] - base;

  float erv[HNUM];
  if (HNUM == 4){
    float4 t = *reinterpret_cast<const float4*>(er + node * 4);
    erv[0] = t.x; erv[1] = t.y; erv[2] = t.z; erv[3] = t.w;
  } else erv[0] = er[node];

  // online max+sum (single pass over el)
  float mx[HNUM], sm[HNUM];
#pragma unroll
  for (int h = 0; h < HNUM; h++){ mx[h] = -INFINITY; sm[h] = 0.f; }
  for (int i = lane; i < deg; i += 64){
    int s = srcs[base + i];
    float e[HNUM];
    if (HNUM == 4){
      float4 t = *reinterpret_cast<const float4*>(el + s * 4);
      e[0] = t.x; e[1] = t.y; e[2] = t.z; e[3] = t.w;
    } else e[0] = el[s];
#pragma unroll
    for (int h = 0; h < HNUM; h++){
      float v = e[h] + erv[h];
      v = v > 0.f ? v : 0.2f * v;
      float mn = fmaxf(mx[h], v);
      sm[h] = sm[h] * __expf(mx[h] - mn) + __expf(v - mn);
      mx[h] = mn;
    }
  }
  float M[HNUM], inv[HNUM];
#pragma unroll
  for (int h = 0; h < HNUM; h++){
    M[h] = wmaxf(mx[h]);
    float sc = sm[h] * __expf(mx[h] - M[h]);
    inv[h] = 1.f / (wsumf(sc) + 1e-9f);
  }

  int l = lane % LL, g = lane / LL;
  float acc[8];
#pragma unroll
  for (int d = 0; d < 8; d++) acc[d] = 0.f;

  for (int c0 = 0; c0 < deg; c0 += 128){
    int cnt = min(128, deg - c0);
    for (int i = lane; i < cnt; i += 64){
      int s = srcs[base + c0 + i];
      sids[i] = s;
      float e[HNUM], a[HNUM], wsum = 0.f;
      if (HNUM == 4){
        float4 t = *reinterpret_cast<const float4*>(el + s * 4);
        e[0] = t.x; e[1] = t.y; e[2] = t.z; e[3] = t.w;
      } else e[0] = el[s];
#pragma unroll
      for (int h = 0; h < HNUM; h++){
        float v = e[h] + erv[h];
        v = v > 0.f ? v : 0.2f * v;
        a[h] = __expf(v - M[h]) * inv[h];
        wsum += a[h];
      }
      if (HNUM == 4)
        *reinterpret_cast<float4*>(&alds[i * 4]) = make_float4(a[0], a[1], a[2], a[3]);
      else
        alds[i] = a[0];
      wsum *= (1.f / (3.f * HNUM));
      int eidx = base + c0 + i;
      wE[eidx] = init_w ? wsum : (wE[eidx] + wsum);
    }
    __syncthreads();
    for (int j0 = 0; j0 < cnt; j0 += EP){
      int j = j0 + g;
      if (j < cnt){
        int s = sids[j];
        float a = (HNUM == 4) ? alds[j * 4 + (l >> 2)] : alds[j];
        uint4 v = hb[(size_t)s * RS + l];
        acc[0] += a * bflo(v.x); acc[1] += a * bfhi(v.x);
        acc[2] += a * bflo(v.y); acc[3] += a * bfhi(v.y);
        acc[4] += a * bflo(v.z); acc[5] += a * bfhi(v.z);
        acc[6] += a * bflo(v.w); acc[7] += a * bfhi(v.w);
      }
    }
    __syncthreads();
  }
#pragma unroll
  for (int off = LL; off < 64; off <<= 1)
#pragma unroll
    for (int d = 0; d < 8; d++) acc[d] += __shfl_xor(acc[d], off, 64);

  if (EPI == 0){
    if (g == 0){
      float o[8];
#pragma unroll
      for (int d = 0; d < 8; d++) o[d] = acc[d] > 0.f ? acc[d] : expm1f(acc[d]);
      float4* dst4 = reinterpret_cast<float4*>(outp + (size_t)node * MDIM + 8 * l);
      dst4[0] = make_float4(o[0], o[1], o[2], o[3]);
      dst4[1] = make_float4(o[4], o[5], o[6], o[7]);
    }
  } else {
    // all lanes hold full-row values for classes 8l..8l+7 (LL=8)
    float m8 = acc[0];
#pragma unroll
    for (int d = 1; d < 8; d++) m8 = fmaxf(m8, acc[d]);
#pragma unroll
    for (int off = 1; off < 8; off <<= 1) m8 = fmaxf(m8, __shfl_xor(m8, off, 64));
    float p[8], s8 = 0.f;
#pragma unroll
    for (int d = 0; d < 8; d++){ p[d] = __expf(acc[d] - m8); s8 += p[d]; }
#pragma unroll
    for (int off = 1; off < 8; off <<= 1) s8 += __shfl_xor(s8, off, 64);
    float is = 1.f / s8;
    if (g == 0){
      uint4 pk;
      pk.x = packbf2(p[0] * is, p[1] * is);
      pk.y = packbf2(p[2] * is, p[3] * is);
      pk.z = packbf2(p[4] * is, p[5] * is);
      pk.w = packbf2(p[6] * is, p[7] * is);
      *reinterpret_cast<uint4*>((unsigned short*)outb + (size_t)node * 64 + 8 * l) = pk;
    }
  }
}

// ---------------- LP aggregation: agg[dst] = sum_e w[e]*pseudo_bf16[src] ----
__global__ __launch_bounds__(256) void k_agg(
    const int* __restrict__ ptre, const int2* __restrict__ epk,
    const uint4* __restrict__ pb, float* __restrict__ agg, int n)
{
  int w = threadIdx.x >> 6, lane = threadIdx.x & 63;
  int node = blockIdx.x * 4 + w;
  if (node >= n) return;
  int l = lane & 7, g = lane >> 3;
  int base = ptre[node], deg = ptre[node + 1] - base;
  float acc[8];
#pragma unroll
  for (int d = 0; d < 8; d++) acc[d] = 0.f;
  for (int j0 = 0; j0 < deg; j0 += 8){
    int j = j0 + g;
    if (j < deg){
      int2 ep = epk[base + j];
      float wv = __int_as_float(ep.y);
      uint4 v = pb[(size_t)ep.x * 8 + l];
      acc[0] += wv * bflo(v.x); acc[1] += wv * bfhi(v.x);
      acc[2] += wv * bflo(v.y); acc[3] += wv * bfhi(v.y);
      acc[4] += wv * bflo(v.z); acc[5] += wv * bfhi(v.z);
      acc[6] += wv * bflo(v.w); acc[7] += wv * bfhi(v.w);
    }
  }
#pragma unroll
  for (int off = 8; off < 64; off <<= 1)
#pragma unroll
    for (int d = 0; d < 8; d++) acc[d] += __shfl_xor(acc[d], off, 64);
  if (g == 0){
    float4* o = reinterpret_cast<float4*>(agg + (size_t)node * 64 + 8 * l);
    o[0] = make_float4(acc[0], acc[1], acc[2], acc[3]);
    o[1] = make_float4(acc[4], acc[5], acc[6], acc[7]);
  }
}

// ---------------- launch ----------------
extern "C" void kernel_launch(void* const* d_in, const int* in_sizes, int n_in,
                              void* d_out, int out_size, void* d_ws, size_t ws_size,
                              hipStream_t stream) {
  const float* feat = (const float*)d_in[0];
  const int*   src  = (const int*)d_in[1];
  const int*   dst  = (const int*)d_in[2];
  const float* W0   = (const float*)d_in[3];
  const float* al0  = (const float*)d_in[4];
  const float* ar0  = (const float*)d_in[5];
  const float* W1   = (const float*)d_in[6];
  const float* al1  = (const float*)d_in[7];
  const float* ar1  = (const float*)d_in[8];
  const float* W2   = (const float*)d_in[9];
  const float* al2  = (const float*)d_in[10];
  const float* ar2  = (const float*)d_in[11];
  const float* Wp   = (const float*)d_in[12];
  const float* bp   = (const float*)d_in[13];
  float* out = (float*)d_out;

  const int N = in_sizes[0] / 256;
  const int E = in_sizes[1];
  const int NCH = (N + 255) / 256;

  char* p = (char*)d_ws;
  auto carve = [&](size_t bytes) -> void* {
    void* r = (void*)p;
    p += (bytes + 255) & ~(size_t)255;
    return r;
  };
  int*   ptr_i = (int*)carve((size_t)(N + 1) * 4);
  int*   cntA  = (int*)carve((size_t)N * 4);
  int*   cntB  = (int*)carve((size_t)N * 4);
  int*   sums  = (int*)carve(1024);
  int*   chof  = (int*)carve(1024);
  int*   srcs  = (int*)carve((size_t)E * 4);
  float* wE    = (float*)carve((size_t)E * 4);
  float* hbuf  = (float*)carve((size_t)N * 128 * 4);
  float* xbuf  = (float*)carve((size_t)N * 128 * 4);
  unsigned int* hb = (unsigned int*)carve((size_t)N * 128 * 2);   // bf16 h
  float* el    = (float*)carve((size_t)N * 4 * 4);
  float* er    = (float*)carve((size_t)N * 4 * 4);
  unsigned int* pbA = (unsigned int*)carve((size_t)N * 64 * 2);   // bf16 pseudo
  unsigned int* pbB = (unsigned int*)carve((size_t)N * 64 * 2);
  int2*  epk    = (int2*)xbuf;     // overlays xbuf (dead after GEMM2)
  float* aggbuf = hbuf;            // overlays hbuf (dead after last k_elr)
  (void)ws_size; (void)n_in; (void)out_size;

  // ---- CSR by dst ----
  k_zero2<<<(N + 255) / 256, 256, 0, stream>>>(cntA, cntB, N);
  k_hist<<<(E + 255) / 256, 256, 0, stream>>>(dst, cntA, E);
  k_scan1<<<NCH, 256, 0, stream>>>(cntA, ptr_i, sums, N);
  k_scan2<<<1, 256, 0, stream>>>(sums, chof, NCH);
  k_scan3<<<NCH, 256, 0, stream>>>(ptr_i, chof, N, E);
  k_fill<<<(E + 255) / 256, 256, 0, stream>>>(src, dst, ptr_i, cntB, srcs, E);

  const int GG = (N + 63) / 64;
  // ---- layer 0: 256 -> [4,32] ----
  k_gemm<128, 0><<<GG, 256, 0, stream>>>(feat, W0, nullptr, hbuf, hb, N, 256);
  k_elr<4, 32><<<(N * 4 + 255) / 256, 256, 0, stream>>>(hbuf, al0, ar0, el, er, N);
  k_edge<4, 128, 0><<<N, 64, 0, stream>>>(ptr_i, srcs, (const uint4*)hb, el, er, xbuf, nullptr, wE, 1, N);
  // ---- layer 1: 128 -> [4,32] ----
  k_gemm<128, 0><<<GG, 256, 0, stream>>>(xbuf, W1, nullptr, hbuf, hb, N, 128);
  k_elr<4, 32><<<(N * 4 + 255) / 256, 256, 0, stream>>>(hbuf, al1, ar1, el, er, N);
  k_edge<4, 128, 0><<<N, 64, 0, stream>>>(ptr_i, srcs, (const uint4*)hb, el, er, xbuf, nullptr, wE, 0, N);
  // ---- layer 2: 128 -> [1,64] ----
  k_gemm<64, 0><<<GG, 256, 0, stream>>>(xbuf, W2, nullptr, hbuf, hb, N, 128);
  k_elr<1, 64><<<(N + 255) / 256, 256, 0, stream>>>(hbuf, al2, ar2, el, er, N);
  k_edge<1, 64, 1><<<N, 64, 0, stream>>>(ptr_i, srcs, (const uint4*)hb, el, er, nullptr, pbA, wE, 0, N);

  // ---- pack (src, w) for LP gathers ----
  k_pack<<<(E + 255) / 256, 256, 0, stream>>>(srcs, wE, epk, E);

  // ---- 10 label-prop steps ----
  unsigned int* cur = pbA; unsigned int* nxt = pbB;
  for (int st = 0; st < 10; st++){
    k_agg<<<(N + 3) / 4, 256, 0, stream>>>(ptr_i, epk, (const uint4*)cur, aggbuf, N);
    if (st == 9)
      k_gemm<64, 2><<<GG, 256, 0, stream>>>(aggbuf, Wp, bp, out, nullptr, N, 64);
    else
      k_gemm<64, 1><<<GG, 256, 0, stream>>>(aggbuf, Wp, bp, nullptr, nxt, N, 64);
    unsigned int* t = cur; cur = nxt; nxt = t;
  }
}